// Round 10
// baseline (2258.705 us; speedup 1.0000x reference)
//
#include <hip/hip_runtime.h>
#include <hip/hip_bf16.h>
#include <math.h>

#define LQ 512
#define HH 512
#define EE 300
#define WW 20
#define G4 2048
#define EPSF 1e-8f
#define RB 16   // blocks per LSTM in recurrence
#define JPB 32  // j (h-elements) per block

typedef __hip_bfloat16 bf16;
typedef unsigned long long u64;
typedef unsigned int u32;

__device__ __forceinline__ float fast_sigmoid(float x){
  x = fminf(fmaxf(x, -30.f), 30.f);
  return 1.f/(1.f + __expf(-x));
}
__device__ __forceinline__ float fast_tanh(float x){
  x = fminf(fmaxf(x, -15.f), 15.f);
  float e = __expf(2.f*x);
  return (e - 1.f)/(e + 1.f);
}

// ---- workspace layout (float offsets) ----
#define OFF_GIN   0
#define OFF_ALPHA 0                      // overlays gin after k_lstm
#define OFF_ATT   524288
#define OFF_NRM   1048576
#define OFF_NP    1089536
#define OFF_HS    (4*LQ*G4)              // 4194304
#define OFF_HPUB  (OFF_HS + 4*LQ*HH)     // 5242880 (u64 region)
#define WS_NEEDED ((OFF_HPUB + 2*4*LQ*HH) * 4ULL)

__device__ __forceinline__ float blk_sum(float v, float* scr, int tid){
  #pragma unroll
  for (int o=32;o>0;o>>=1) v += __shfl_down(v, o);
  __syncthreads();
  if ((tid & 63) == 0) scr[tid>>6] = v;
  __syncthreads();
  return scr[0]+scr[1]+scr[2]+scr[3];
}

__global__ __launch_bounds__(256) void k_sentinel(float* __restrict__ outp, float code)
{
  const int i = blockIdx.x*256 + threadIdx.x;
  if (i < 3072) outp[i] = code;
}

// ============ 1. embedding gather + Wih GEMM ============
__global__ __launch_bounds__(256) void k_gather_gemm(
    const float* __restrict__ emb, const int* __restrict__ q1_ids, const int* __restrict__ q2_ids,
    const float* __restrict__ wih0, const float* __restrict__ wih1,
    const float* __restrict__ wih2, const float* __restrict__ wih3,
    float* __restrict__ gin)
{
  const int g = blockIdx.z;
  const int* ids = (g < 2) ? q1_ids : q2_ids;
  const float* wih = (g==0)?wih0:(g==1)?wih1:(g==2)?wih2:wih3;
  __shared__ float As[16][68];
  __shared__ float Bs[16][68];
  __shared__ int rowid[64];
  const int tid = threadIdx.x;
  const int tx = tid & 15, ty = tid >> 4;
  const int m0 = blockIdx.y*64, n0 = blockIdx.x*64;
  if (tid < 64) rowid[tid] = ids[m0 + tid];
  __syncthreads();
  float acc[4][4] = {};
  for (int k0 = 0; k0 < EE; k0 += 16) {
    for (int idx = tid; idx < 1024; idx += 256) {
      int r = idx >> 4, kk = idx & 15;
      int k = k0 + kk;
      As[kk][r] = (k < EE) ? emb[(size_t)rowid[r]*EE + k] : 0.f;
      Bs[kk][r] = (k < EE) ? wih[(size_t)(n0+r)*EE + k] : 0.f;
    }
    __syncthreads();
    #pragma unroll
    for (int kk=0;kk<16;kk++){
      float a[4], b[4];
      #pragma unroll
      for (int u=0;u<4;u++) a[u]=As[kk][ty*4+u];
      #pragma unroll
      for (int v=0;v<4;v++) b[v]=Bs[kk][tx*4+v];
      #pragma unroll
      for (int u=0;u<4;u++)
        #pragma unroll
        for (int v=0;v<4;v++) acc[u][v] = fmaf(a[u], b[v], acc[u][v]);
    }
    __syncthreads();
  }
  float* outp = gin + (size_t)g*LQ*G4;
  #pragma unroll
  for (int u=0;u<4;u++)
    #pragma unroll
    for (int v=0;v<4;v++)
      outp[(size_t)(m0+ty*4+u)*G4 + n0+tx*4+v] = acc[u][v];
}

// ============ 2. LSTM recurrence v3 ============
// 1024 thr/block, 64 weights/thread (register-resident target), lane map
// lane = j_local*32 + gate*8 + hchunk -> shuffle-only reduction, c in register,
// double-buffered h_lds -> ONE barrier/step, AGENT scope, tight poll.
__global__ __launch_bounds__(1024, 4) void k_lstm(
    const float* __restrict__ whh0, const float* __restrict__ whh1,
    const float* __restrict__ whh2, const float* __restrict__ whh3,
    const float* __restrict__ gin, float* __restrict__ hs, u64* __restrict__ hpub)
{
  const int g = (blockIdx.x >> 1) & 3;                       // XCD pair {2g,2g+1}
  const int b = ((blockIdx.x >> 3) << 1) | (blockIdx.x & 1); // 0..15
  const float* whh = (g==0)?whh0:(g==1)?whh1:(g==2)?whh2:whh3;
  const int tid  = threadIdx.x;
  const int wave = tid >> 6;
  const int lane = tid & 63;
  const int jl   = lane >> 5;          // 0..1
  const int gate = (lane >> 3) & 3;    // 0..3
  const int hc   = lane & 7;           // 0..7 (64-wide h chunks)
  const int j    = wave*2 + jl;        // 0..31
  const int jglob = b*JPB + j;
  const int grow = gate*HH + jglob;
  const int rot  = hc*2;               // float4-rotation (bank decollision)

  // 64 weights, pre-rotated: w[q*4+e] = Whh[grow][hc*64 + ((q+rot)&15)*4 + e]
  float w[64];
  {
    const float4* wv4 = reinterpret_cast<const float4*>(whh + (size_t)grow*HH + hc*64);
    #pragma unroll
    for (int q=0;q<16;q++){
      float4 u = wv4[(q + rot) & 15];
      w[q*4+0]=u.x; w[q*4+1]=u.y; w[q*4+2]=u.z; w[q*4+3]=u.w;
    }
  }
  __shared__ __align__(16) float h_lds[2][HH];
  const bool comb = ((lane & 31) == 0);
  float creg = 0.f;
  if (tid < HH) h_lds[0][tid] = 0.f;
  __syncthreads();

  const float* ginp = gin + (size_t)g*LQ*G4;
  float* hsg = hs + (size_t)g*LQ*HH;
  u64* hpg = hpub + (size_t)g*LQ*HH;
  const bool fwd = ((g & 1) == 0);

  for (int s=0; s<LQ; ++s) {
    const int buf = s & 1;
    const int sidx = fwd ? s : (LQ-1-s);
    // combiner prefetches its 4 gate biases before the poll
    float pgi=0.f, pgf=0.f, pgg=0.f, pgo=0.f;
    if (comb) {
      const float* gb = ginp + (size_t)sidx*G4 + jglob;
      pgi = gb[0]; pgf = gb[HH]; pgg = gb[2*HH]; pgo = gb[3*HH];
    }
    if (s > 0) {
      const int hidx = fwd ? (s-1) : (LQ-s);
      if (tid < HH) {
        const u64 want = (u64)(u32)(hidx + 1);
        const u64* hp = hpg + (size_t)hidx*HH + tid;
        u64 v = __hip_atomic_load(hp, __ATOMIC_RELAXED, __HIP_MEMORY_SCOPE_AGENT);
        while ((v >> 32) != want) {
          v = __hip_atomic_load(hp, __ATOMIC_RELAXED, __HIP_MEMORY_SCOPE_AGENT);
        }
        h_lds[buf][tid] = __uint_as_float((u32)v);
      }
      __syncthreads();
    }
    // 64-wide rotated matvec, 4 accumulator chains
    float p0=0.f, p1=0.f, p2=0.f, p3=0.f;
    {
      const float4* h4 = reinterpret_cast<const float4*>(h_lds[buf]) + (hc << 4);
      #pragma unroll
      for (int q=0;q<16;q+=4){
        float4 a0 = h4[(q+0 + rot) & 15];
        float4 a1 = h4[(q+1 + rot) & 15];
        float4 a2 = h4[(q+2 + rot) & 15];
        float4 a3 = h4[(q+3 + rot) & 15];
        p0 = fmaf(w[(q+0)*4+0], a0.x, p0); p0 = fmaf(w[(q+0)*4+1], a0.y, p0);
        p0 = fmaf(w[(q+0)*4+2], a0.z, p0); p0 = fmaf(w[(q+0)*4+3], a0.w, p0);
        p1 = fmaf(w[(q+1)*4+0], a1.x, p1); p1 = fmaf(w[(q+1)*4+1], a1.y, p1);
        p1 = fmaf(w[(q+1)*4+2], a1.z, p1); p1 = fmaf(w[(q+1)*4+3], a1.w, p1);
        p2 = fmaf(w[(q+2)*4+0], a2.x, p2); p2 = fmaf(w[(q+2)*4+1], a2.y, p2);
        p2 = fmaf(w[(q+2)*4+2], a2.z, p2); p2 = fmaf(w[(q+2)*4+3], a2.w, p2);
        p3 = fmaf(w[(q+3)*4+0], a3.x, p3); p3 = fmaf(w[(q+3)*4+1], a3.y, p3);
        p3 = fmaf(w[(q+3)*4+2], a3.z, p3); p3 = fmaf(w[(q+3)*4+3], a3.w, p3);
      }
    }
    float d = (p0 + p1) + (p2 + p3);
    // sum over 8 h-chunks (lane bits 0-2)
    d += __shfl_xor(d, 1);
    d += __shfl_xor(d, 2);
    d += __shfl_xor(d, 4);
    // gather the 4 gate dots (lane bits 3-4) to the combiner
    float dF = __shfl_xor(d, 8);
    float dG = __shfl_xor(d, 16);
    float dO = __shfl_xor(d, 24);
    if (comb) {
      float gi = d  + pgi;
      float gf = dF + pgf;
      float gg = dG + pgg;
      float go = dO + pgo;
      creg = fast_sigmoid(gf)*creg + fast_sigmoid(gi)*fast_tanh(gg);
      float h = fast_sigmoid(go)*fast_tanh(creg);
      u64 pack = ((u64)(u32)(sidx + 1) << 32) | (u64)__float_as_uint(h);
      __hip_atomic_store(hpg + (size_t)sidx*HH + jglob, pack,
                         __ATOMIC_RELAXED, __HIP_MEMORY_SCOPE_AGENT);
      hsg[(size_t)sidx*HH + jglob] = h;
    }
  }
}

// ============ 3. norms (block reduction) ============
__global__ __launch_bounds__(256) void k_norms(
    const float* __restrict__ hs, const float* __restrict__ W3, const float* __restrict__ W4,
    float* __restrict__ nrm, float* __restrict__ np_)
{
  const int l = blockIdx.x;
  const int which = blockIdx.y;  // 0:q1p/W3 1:q2p/W3 2:q1n/W4 3:q2n/W4
  const int hsidx = (which==0)?0:(which==1)?2:(which==2)?1:3;
  const float* P = hs + (size_t)hsidx*LQ*HH + (size_t)l*HH;
  const float* Wt = (which < 2) ? W3 : W4;
  const int tid = threadIdx.x;
  __shared__ float p[HH];
  __shared__ float scr[4];
  p[tid] = P[tid]; p[tid+256] = P[tid+256];
  __syncthreads();
  {
    float v = p[tid]*p[tid] + p[tid+256]*p[tid+256];
    float s = blk_sum(v, scr, tid);
    if (tid==0) np_[which*LQ + l] = fmaxf(sqrtf(s), EPSF);
  }
  for (int k=0;k<WW;k++){
    float w1 = Wt[(size_t)k*HH + tid];
    float w2 = Wt[(size_t)k*HH + tid+256];
    float a1 = p[tid]*w1, a2 = p[tid+256]*w2;
    float s = blk_sum(a1*a1 + a2*a2, scr, tid);
    if (tid==0) nrm[(size_t)which*LQ*WW + (size_t)l*WW + k] = fmaxf(sqrtf(s), EPSF);
  }
}

// ============ 4. alpha = cos_pair (tiled NT GEMM) ============
__global__ __launch_bounds__(256) void k_alpha(
    const float* __restrict__ hs, const float* __restrict__ np_, float* __restrict__ alpha)
{
  const int z = blockIdx.z;
  const float* A = hs + (size_t)(z?1:0)*LQ*HH;
  const float* B = hs + (size_t)(z?3:2)*LQ*HH;
  const float* nai = np_ + (z?2:0)*LQ;
  const float* nbj = np_ + (z?3:1)*LQ;
  float* outp = alpha + (size_t)z*LQ*LQ;
  __shared__ float As[16][68], Bs[16][68];
  const int tid = threadIdx.x;
  const int tx = tid & 15, ty = tid >> 4;
  const int i0 = blockIdx.y*64, j0 = blockIdx.x*64;
  float acc[4][4] = {};
  for (int k0=0;k0<HH;k0+=16){
    for (int idx=tid; idx<1024; idx+=256){
      int r = idx>>4, kk = idx&15;
      As[kk][r] = A[(size_t)(i0+r)*HH + k0+kk];
      Bs[kk][r] = B[(size_t)(j0+r)*HH + k0+kk];
    }
    __syncthreads();
    #pragma unroll
    for (int kk=0;kk<16;kk++){
      float a[4], b[4];
      #pragma unroll
      for (int u=0;u<4;u++) a[u]=As[kk][ty*4+u];
      #pragma unroll
      for (int v=0;v<4;v++) b[v]=Bs[kk][tx*4+v];
      #pragma unroll
      for (int u=0;u<4;u++)
        #pragma unroll
        for (int v=0;v<4;v++) acc[u][v] = fmaf(a[u], b[v], acc[u][v]);
    }
    __syncthreads();
  }
  #pragma unroll
  for (int u=0;u<4;u++){
    float ina = 1.f/nai[i0+ty*4+u];
    #pragma unroll
    for (int v=0;v<4;v++)
      outp[(size_t)(i0+ty*4+u)*LQ + j0+tx*4+v] = acc[u][v]*ina/nbj[j0+tx*4+v];
  }
}

// ============ 5. attention (tiled NN GEMM, rowsum fused) ============
__global__ __launch_bounds__(256) void k_att(
    const float* __restrict__ alpha, const float* __restrict__ hs,
    float* __restrict__ att)
{
  const int z = blockIdx.z;
  const float* A = alpha + (size_t)z*LQ*LQ;
  const float* B = hs + (size_t)(z?3:2)*LQ*HH;
  float* outp = att + (size_t)z*LQ*HH;
  __shared__ float As[16][68], Bs[16][68];
  const int tid = threadIdx.x;
  const int tx = tid & 15, ty = tid >> 4;
  const int i0 = blockIdx.y*64, h0 = blockIdx.x*64;
  float acc[4][4] = {};
  float rsum[4] = {};
  for (int j0=0;j0<LQ;j0+=16){
    for (int idx=tid; idx<1024; idx+=256){
      int r = idx>>4, kk = idx&15;
      As[kk][r] = A[(size_t)(i0+r)*LQ + j0+kk];
    }
    for (int idx=tid; idx<1024; idx+=256){
      int jjr = idx>>6, hh = idx&63;
      Bs[jjr][hh] = B[(size_t)(j0+jjr)*HH + h0+hh];
    }
    __syncthreads();
    #pragma unroll
    for (int kk=0;kk<16;kk++){
      float a[4], b[4];
      #pragma unroll
      for (int u=0;u<4;u++){ a[u]=As[kk][ty*4+u]; rsum[u] += a[u]; }
      #pragma unroll
      for (int v=0;v<4;v++) b[v]=Bs[kk][tx*4+v];
      #pragma unroll
      for (int u=0;u<4;u++)
        #pragma unroll
        for (int v=0;v<4;v++) acc[u][v] = fmaf(a[u], b[v], acc[u][v]);
    }
    __syncthreads();
  }
  #pragma unroll
  for (int u=0;u<4;u++){
    float inv = 1.f/rsum[u];
    #pragma unroll
    for (int v=0;v<4;v++)
      outp[(size_t)(i0+ty*4+u)*HH + h0+tx*4+v] = acc[u][v]*inv;
  }
}

// ============ 6. fused wcos_rows: outputs m = 0,1,4,5 ============
__global__ __launch_bounds__(256) void k_wcos(
    const float* __restrict__ hs, const float* __restrict__ att,
    const float* __restrict__ W1, const float* __restrict__ W2, const float* __restrict__ W5,
    float* __restrict__ outp)
{
  const int l = blockIdx.x;
  const int which = blockIdx.y;
  const int tid = threadIdx.x;
  const float* a; const float* c; const float* Wt; int m;
  switch (which) {
    case 0:  a = hs + (size_t)0*LQ*HH + (size_t)l*HH; c = hs + (size_t)2*LQ*HH + (size_t)(LQ-1)*HH; Wt = W1; m = 0; break;
    case 1:  a = hs + (size_t)1*LQ*HH + (size_t)l*HH; c = hs + (size_t)3*LQ*HH;                     Wt = W2; m = 1; break;
    case 2:  a = hs + (size_t)0*LQ*HH + (size_t)l*HH; c = att + (size_t)0*LQ*HH + (size_t)l*HH;     Wt = W5; m = 4; break;
    default: a = hs + (size_t)1*LQ*HH + (size_t)l*HH; c = att + (size_t)1*LQ*HH + (size_t)l*HH;     Wt = W5; m = 5; break;
  }
  __shared__ float av[HH], cv[HH];
  __shared__ float scr[4];
  av[tid]=a[tid]; av[tid+256]=a[tid+256];
  cv[tid]=c[tid]; cv[tid+256]=c[tid+256];
  __syncthreads();
  for (int k=0;k<WW;k++){
    float w1 = Wt[(size_t)k*HH+tid];
    float w2 = Wt[(size_t)k*HH+tid+256];
    float aw1=av[tid]*w1, aw2=av[tid+256]*w2;
    float cw1=cv[tid]*w1, cw2=cv[tid+256]*w2;
    float num = blk_sum(aw1*cw1 + aw2*cw2, scr, tid);
    float na  = blk_sum(aw1*aw1 + aw2*aw2, scr, tid);
    float nc  = blk_sum(cw1*cw1 + cw2*cw2, scr, tid);
    if (tid==0){
      float d = fmaxf(sqrtf(na),EPSF)*fmaxf(sqrtf(nc),EPSF);
      outp[((size_t)m*LQ + l)*WW + k] = num/d;
    }
  }
}

// ============ 7. pair_max (tiled GEMM w/ fused max over j): outputs m = 2,3 ============
__global__ __launch_bounds__(256) void k_pairmax(
    const float* __restrict__ hs, const float* __restrict__ W3, const float* __restrict__ W4,
    const float* __restrict__ nrm, float* __restrict__ outp)
{
  const int k  = blockIdx.x;   // 0..19
  const int it = blockIdx.y;   // 0..7
  const int mm = blockIdx.z;   // 0:pos 1:neg
  const float* A = hs + (size_t)(mm?1:0)*LQ*HH;
  const float* B = hs + (size_t)(mm?3:2)*LQ*HH;
  const float* Wt = mm ? W4 : W3;
  const float* na = nrm + (size_t)(mm?2:0)*LQ*WW;
  const float* nb = nrm + (size_t)(mm?3:1)*LQ*WW;
  const int tid = threadIdx.x;
  const int tx = tid & 15, ty = tid >> 4;
  __shared__ float w2[HH];
  __shared__ float nbinv[LQ];
  __shared__ float As[16][68], Bs[16][68];
  for (int h=tid; h<HH; h+=256){ float wv = Wt[(size_t)k*HH + h]; w2[h]=wv*wv; }
  for (int j=tid; j<LQ; j+=256){ nbinv[j] = 1.f/nb[(size_t)j*WW + k]; }
  __syncthreads();
  const int i0 = it*64;
  float vmax[4] = {-3.4e38f,-3.4e38f,-3.4e38f,-3.4e38f};
  for (int j0=0;j0<LQ;j0+=64){
    float acc[4][4] = {};
    for (int k0=0;k0<HH;k0+=16){
      for (int idx=tid; idx<1024; idx+=256){
        int r=idx>>4, kk=idx&15;
        As[kk][r] = A[(size_t)(i0+r)*HH + k0+kk] * w2[k0+kk];
      }
      for (int idx=tid; idx<1024; idx+=256){
        int r=idx>>4, kk=idx&15;
        Bs[kk][r] = B[(size_t)(j0+r)*HH + k0+kk];
      }
      __syncthreads();
      #pragma unroll
      for (int kk=0;kk<16;kk++){
        float a[4], b[4];
        #pragma unroll
        for (int u=0;u<4;u++) a[u]=As[kk][ty*4+u];
        #pragma unroll
        for (int v=0;v<4;v++) b[v]=Bs[kk][tx*4+v];
        #pragma unroll
        for (int u=0;u<4;u++)
          #pragma unroll
          for (int v=0;v<4;v++) acc[u][v] = fmaf(a[u], b[v], acc[u][v]);
      }
      __syncthreads();
    }
    #pragma unroll
    for (int v=0;v<4;v++){
      float nv = nbinv[j0+tx*4+v];
      #pragma unroll
      for (int u=0;u<4;u++)
        vmax[u] = fmaxf(vmax[u], acc[u][v]*nv);
    }
  }
  #pragma unroll
  for (int o=1;o<16;o<<=1){
    #pragma unroll
    for (int u=0;u<4;u++)
      vmax[u] = fmaxf(vmax[u], __shfl_xor(vmax[u], o, 16));
  }
  if (tx==0){
    #pragma unroll
    for (int u=0;u<4;u++){
      int i = i0 + ty*4 + u;
      outp[((size_t)(mm+2)*LQ + i)*WW + k] = vmax[u] / na[(size_t)i*WW + k];
    }
  }
}

extern "C" void kernel_launch(void* const* d_in, const int* in_sizes, int n_in,
                              void* d_out, int out_size, void* d_ws, size_t ws_size,
                              hipStream_t stream)
{
  float* outp = (float*)d_out;

  float code = 0.f;
  if (n_in != 19)                    code = 101.f;
  else if (in_sizes[0]  != 512)      code = 102.f;
  else if (in_sizes[4]  != 9000000)  code = 104.f;
  else if (in_sizes[6]  != 1048576)  code = 106.f;
  else if (out_size     != 61440)    code = 108.f;
  else if (ws_size      < WS_NEEDED) code = 109.f;
  if (code != 0.f) {
    k_sentinel<<<12, 256, 0, stream>>>(outp, code);
    return;
  }

  const int* q1_ids = (const int*)d_in[0];
  const int* q2_ids = (const int*)d_in[1];
  const float* emb      = (const float*)d_in[4];
  const float* q1_wih_f = (const float*)d_in[5];
  const float* q1_whh_f = (const float*)d_in[6];
  const float* q1_wih_b = (const float*)d_in[7];
  const float* q1_whh_b = (const float*)d_in[8];
  const float* q2_wih_f = (const float*)d_in[9];
  const float* q2_whh_f = (const float*)d_in[10];
  const float* q2_wih_b = (const float*)d_in[11];
  const float* q2_whh_b = (const float*)d_in[12];
  const float* W1 = (const float*)d_in[13];
  const float* W2 = (const float*)d_in[14];
  const float* W3 = (const float*)d_in[15];
  const float* W4 = (const float*)d_in[16];
  const float* W5 = (const float*)d_in[17];
  float* ws = (float*)d_ws;

  float* gin   = ws + OFF_GIN;
  float* hsv   = ws + OFF_HS;
  u64*   hpub  = (u64*)(ws + OFF_HPUB);
  float* alpha = ws + OFF_ALPHA;
  float* att   = ws + OFF_ATT;
  float* nrm   = ws + OFF_NRM;
  float* np_   = ws + OFF_NP;

  k_gather_gemm<<<dim3(32,8,4), 256, 0, stream>>>(emb, q1_ids, q2_ids,
      q1_wih_f, q1_wih_b, q2_wih_f, q2_wih_b, gin);
  k_lstm<<<dim3(4*RB), 1024, 0, stream>>>(q1_whh_f, q1_whh_b, q2_whh_f, q2_whh_b,
      gin, hsv, hpub);
  k_norms<<<dim3(LQ,4), 256, 0, stream>>>(hsv, W3, W4, nrm, np_);
  k_alpha<<<dim3(8,8,2), 256, 0, stream>>>(hsv, np_, alpha);
  k_att<<<dim3(8,8,2), 256, 0, stream>>>(alpha, hsv, att);
  k_wcos<<<dim3(LQ,4), 256, 0, stream>>>(hsv, att, W1, W2, W5, outp);
  k_pairmax<<<dim3(WW,8,2), 256, 0, stream>>>(hsv, W3, W4, nrm, outp);
}

// Round 11
// 1670.532 us; speedup vs baseline: 1.3521x; 1.3521x over previous
//
#include <hip/hip_runtime.h>
#include <hip/hip_bf16.h>
#include <math.h>

#define LQ 512
#define HH 512
#define EE 300
#define WW 20
#define G4 2048
#define EPSF 1e-8f
#define RB 16   // blocks per LSTM in recurrence
#define JPB 32  // j (h-elements) per block

typedef __hip_bfloat16 bf16;
typedef unsigned long long u64;
typedef unsigned int u32;

__device__ __forceinline__ float fast_sigmoid(float x){
  x = fminf(fmaxf(x, -30.f), 30.f);
  return 1.f/(1.f + __expf(-x));
}
__device__ __forceinline__ float fast_tanh(float x){
  x = fminf(fmaxf(x, -15.f), 15.f);
  float e = __expf(2.f*x);
  return (e - 1.f)/(e + 1.f);
}

// ---- workspace layout (float offsets) ----
#define OFF_GIN   0
#define OFF_ALPHA 0                      // overlays gin after k_lstm
#define OFF_ATT   524288
#define OFF_NRM   1048576
#define OFF_NP    1089536
#define OFF_HS    (4*LQ*G4)              // 4194304
#define OFF_HPUB  (OFF_HS + 4*LQ*HH)     // 5242880 (u64 region)
#define WS_NEEDED ((OFF_HPUB + 2*4*LQ*HH) * 4ULL)

__device__ __forceinline__ float blk_sum(float v, float* scr, int tid){
  #pragma unroll
  for (int o=32;o>0;o>>=1) v += __shfl_down(v, o);
  __syncthreads();
  if ((tid & 63) == 0) scr[tid>>6] = v;
  __syncthreads();
  return scr[0]+scr[1]+scr[2]+scr[3];
}

__global__ __launch_bounds__(256) void k_sentinel(float* __restrict__ outp, float code)
{
  const int i = blockIdx.x*256 + threadIdx.x;
  if (i < 3072) outp[i] = code;
}

// ============ 1. embedding gather + Wih GEMM ============
__global__ __launch_bounds__(256) void k_gather_gemm(
    const float* __restrict__ emb, const int* __restrict__ q1_ids, const int* __restrict__ q2_ids,
    const float* __restrict__ wih0, const float* __restrict__ wih1,
    const float* __restrict__ wih2, const float* __restrict__ wih3,
    float* __restrict__ gin)
{
  const int g = blockIdx.z;
  const int* ids = (g < 2) ? q1_ids : q2_ids;
  const float* wih = (g==0)?wih0:(g==1)?wih1:(g==2)?wih2:wih3;
  __shared__ float As[16][68];
  __shared__ float Bs[16][68];
  __shared__ int rowid[64];
  const int tid = threadIdx.x;
  const int tx = tid & 15, ty = tid >> 4;
  const int m0 = blockIdx.y*64, n0 = blockIdx.x*64;
  if (tid < 64) rowid[tid] = ids[m0 + tid];
  __syncthreads();
  float acc[4][4] = {};
  for (int k0 = 0; k0 < EE; k0 += 16) {
    for (int idx = tid; idx < 1024; idx += 256) {
      int r = idx >> 4, kk = idx & 15;
      int k = k0 + kk;
      As[kk][r] = (k < EE) ? emb[(size_t)rowid[r]*EE + k] : 0.f;
      Bs[kk][r] = (k < EE) ? wih[(size_t)(n0+r)*EE + k] : 0.f;
    }
    __syncthreads();
    #pragma unroll
    for (int kk=0;kk<16;kk++){
      float a[4], b[4];
      #pragma unroll
      for (int u=0;u<4;u++) a[u]=As[kk][ty*4+u];
      #pragma unroll
      for (int v=0;v<4;v++) b[v]=Bs[kk][tx*4+v];
      #pragma unroll
      for (int u=0;u<4;u++)
        #pragma unroll
        for (int v=0;v<4;v++) acc[u][v] = fmaf(a[u], b[v], acc[u][v]);
    }
    __syncthreads();
  }
  float* outp = gin + (size_t)g*LQ*G4;
  #pragma unroll
  for (int u=0;u<4;u++)
    #pragma unroll
    for (int v=0;v<4;v++)
      outp[(size_t)(m0+ty*4+u)*G4 + n0+tx*4+v] = acc[u][v];
}

// ============ 2. LSTM recurrence (R9 structure + register pinning) ============
// waves_per_eu(1,2): only 2 waves/SIMD ever run (64 blocks / 256 CUs) — tell the
// allocator so w[128] is register-resident instead of spilled (R9: VGPR=88+scratch).
__global__ __launch_bounds__(512)
__attribute__((amdgpu_waves_per_eu(1,2)))
void k_lstm(
    const float* __restrict__ whh0, const float* __restrict__ whh1,
    const float* __restrict__ whh2, const float* __restrict__ whh3,
    const float* __restrict__ gin, float* __restrict__ hs, u64* __restrict__ hpub)
{
  const int g = (blockIdx.x >> 1) & 3;                       // XCD pair {2g,2g+1}
  const int b = ((blockIdx.x >> 3) << 1) | (blockIdx.x & 1); // 0..15
  const float* whh = (g==0)?whh0:(g==1)?whh1:(g==2)?whh2:whh3;
  const int tid = threadIdx.x;
  const int row_local = tid >> 2;   // 0..127
  const int chunk = tid & 3;        // 0..3
  const int gate = row_local >> 5;
  const int jj = row_local & 31;
  const int jglob = b*JPB + jj;
  const int grow = gate*HH + jglob;
  const int rot = chunk << 1;       // rotation in float4 units

  // w[q*4+e] = Whh[grow][chunk*128 + ((q+rot)&31)*4 + e]  (pre-rotated)
  float w[128];
  {
    const float4* wv4 = reinterpret_cast<const float4*>(whh + (size_t)grow*HH + chunk*128);
    #pragma unroll
    for (int q=0;q<32;q++){
      float4 u = wv4[(q + rot) & 31];
      w[q*4+0] = u.x; w[q*4+1] = u.y; w[q*4+2] = u.z; w[q*4+3] = u.w;
    }
  }
  __shared__ __align__(16) float h_lds[HH];
  __shared__ float gdot[128];
  __shared__ float c_lds[JPB];
  if (tid < JPB) c_lds[tid] = 0.f;

  const float* ginp = gin + (size_t)g*LQ*G4;
  float* hsg = hs + (size_t)g*LQ*HH;
  u64* hpg = hpub + (size_t)g*LQ*HH;
  const bool fwd = ((g & 1) == 0);

  for (int s=0; s<LQ; ++s) {
    const int sidx = fwd ? s : (LQ-1-s);
    // prefetch gate biases (independent of h) — completes during the spin
    float pgi=0.f, pgf=0.f, pgg=0.f, pgo=0.f;
    if (tid < JPB) {
      const float* gb = ginp + (size_t)sidx*G4;
      const int j = b*JPB + tid;
      pgi = gb[0*HH + j]; pgf = gb[1*HH + j];
      pgg = gb[2*HH + j]; pgo = gb[3*HH + j];
    }
    if (s == 0) {
      h_lds[tid] = 0.f;
      __syncthreads();
    } else {
      const int hidx = fwd ? (s-1) : (LQ-s);
      const u64 want = (u64)(u32)(hidx + 1);
      const u64* hp = hpg + (size_t)hidx*HH + tid;
      u64 v = __hip_atomic_load(hp, __ATOMIC_RELAXED, __HIP_MEMORY_SCOPE_AGENT);
      while ((v >> 32) != want) {
        v = __hip_atomic_load(hp, __ATOMIC_RELAXED, __HIP_MEMORY_SCOPE_AGENT);
      }
      h_lds[tid] = __uint_as_float((u32)v);
      __syncthreads();
    }
    // conflict-free rotated matvec, 4 independent accumulator chains
    float p0=0.f, p1=0.f, p2=0.f, p3=0.f;
    {
      const float4* hld4 = reinterpret_cast<const float4*>(h_lds) + (chunk << 5);
      #pragma unroll
      for (int q=0;q<32;q+=4){
        float4 h0 = hld4[(q+0 + rot) & 31];
        float4 h1 = hld4[(q+1 + rot) & 31];
        float4 h2 = hld4[(q+2 + rot) & 31];
        float4 h3 = hld4[(q+3 + rot) & 31];
        p0 = fmaf(w[(q+0)*4+0], h0.x, p0); p0 = fmaf(w[(q+0)*4+1], h0.y, p0);
        p0 = fmaf(w[(q+0)*4+2], h0.z, p0); p0 = fmaf(w[(q+0)*4+3], h0.w, p0);
        p1 = fmaf(w[(q+1)*4+0], h1.x, p1); p1 = fmaf(w[(q+1)*4+1], h1.y, p1);
        p1 = fmaf(w[(q+1)*4+2], h1.z, p1); p1 = fmaf(w[(q+1)*4+3], h1.w, p1);
        p2 = fmaf(w[(q+2)*4+0], h2.x, p2); p2 = fmaf(w[(q+2)*4+1], h2.y, p2);
        p2 = fmaf(w[(q+2)*4+2], h2.z, p2); p2 = fmaf(w[(q+2)*4+3], h2.w, p2);
        p3 = fmaf(w[(q+3)*4+0], h3.x, p3); p3 = fmaf(w[(q+3)*4+1], h3.y, p3);
        p3 = fmaf(w[(q+3)*4+2], h3.z, p3); p3 = fmaf(w[(q+3)*4+3], h3.w, p3);
      }
    }
    float partial = (p0 + p1) + (p2 + p3);
    partial += __shfl_xor(partial, 1);
    partial += __shfl_xor(partial, 2);
    if (chunk == 0) gdot[row_local] = partial;
    __syncthreads();
    if (tid < JPB) {
      const int j = b*JPB + tid;
      float gi = gdot[tid]         + pgi;
      float gf = gdot[JPB + tid]   + pgf;
      float gg = gdot[2*JPB + tid] + pgg;
      float go = gdot[3*JPB + tid] + pgo;
      float c = fast_sigmoid(gf)*c_lds[tid] + fast_sigmoid(gi)*fast_tanh(gg);
      float h = fast_sigmoid(go)*fast_tanh(c);
      c_lds[tid] = c;
      u64 pack = ((u64)(u32)(sidx + 1) << 32) | (u64)__float_as_uint(h);
      __hip_atomic_store(hpg + (size_t)sidx*HH + j, pack,
                         __ATOMIC_RELAXED, __HIP_MEMORY_SCOPE_AGENT);
      hsg[(size_t)sidx*HH + j] = h;
    }
  }
}

// ============ 3. norms (block reduction) ============
__global__ __launch_bounds__(256) void k_norms(
    const float* __restrict__ hs, const float* __restrict__ W3, const float* __restrict__ W4,
    float* __restrict__ nrm, float* __restrict__ np_)
{
  const int l = blockIdx.x;
  const int which = blockIdx.y;  // 0:q1p/W3 1:q2p/W3 2:q1n/W4 3:q2n/W4
  const int hsidx = (which==0)?0:(which==1)?2:(which==2)?1:3;
  const float* P = hs + (size_t)hsidx*LQ*HH + (size_t)l*HH;
  const float* Wt = (which < 2) ? W3 : W4;
  const int tid = threadIdx.x;
  __shared__ float p[HH];
  __shared__ float scr[4];
  p[tid] = P[tid]; p[tid+256] = P[tid+256];
  __syncthreads();
  {
    float v = p[tid]*p[tid] + p[tid+256]*p[tid+256];
    float s = blk_sum(v, scr, tid);
    if (tid==0) np_[which*LQ + l] = fmaxf(sqrtf(s), EPSF);
  }
  for (int k=0;k<WW;k++){
    float w1 = Wt[(size_t)k*HH + tid];
    float w2 = Wt[(size_t)k*HH + tid+256];
    float a1 = p[tid]*w1, a2 = p[tid+256]*w2;
    float s = blk_sum(a1*a1 + a2*a2, scr, tid);
    if (tid==0) nrm[(size_t)which*LQ*WW + (size_t)l*WW + k] = fmaxf(sqrtf(s), EPSF);
  }
}

// ============ 4. alpha = cos_pair (tiled NT GEMM) ============
__global__ __launch_bounds__(256) void k_alpha(
    const float* __restrict__ hs, const float* __restrict__ np_, float* __restrict__ alpha)
{
  const int z = blockIdx.z;
  const float* A = hs + (size_t)(z?1:0)*LQ*HH;
  const float* B = hs + (size_t)(z?3:2)*LQ*HH;
  const float* nai = np_ + (z?2:0)*LQ;
  const float* nbj = np_ + (z?3:1)*LQ;
  float* outp = alpha + (size_t)z*LQ*LQ;
  __shared__ float As[16][68], Bs[16][68];
  const int tid = threadIdx.x;
  const int tx = tid & 15, ty = tid >> 4;
  const int i0 = blockIdx.y*64, j0 = blockIdx.x*64;
  float acc[4][4] = {};
  for (int k0=0;k0<HH;k0+=16){
    for (int idx=tid; idx<1024; idx+=256){
      int r = idx>>4, kk = idx&15;
      As[kk][r] = A[(size_t)(i0+r)*HH + k0+kk];
      Bs[kk][r] = B[(size_t)(j0+r)*HH + k0+kk];
    }
    __syncthreads();
    #pragma unroll
    for (int kk=0;kk<16;kk++){
      float a[4], b[4];
      #pragma unroll
      for (int u=0;u<4;u++) a[u]=As[kk][ty*4+u];
      #pragma unroll
      for (int v=0;v<4;v++) b[v]=Bs[kk][tx*4+v];
      #pragma unroll
      for (int u=0;u<4;u++)
        #pragma unroll
        for (int v=0;v<4;v++) acc[u][v] = fmaf(a[u], b[v], acc[u][v]);
    }
    __syncthreads();
  }
  #pragma unroll
  for (int u=0;u<4;u++){
    float ina = 1.f/nai[i0+ty*4+u];
    #pragma unroll
    for (int v=0;v<4;v++)
      outp[(size_t)(i0+ty*4+u)*LQ + j0+tx*4+v] = acc[u][v]*ina/nbj[j0+tx*4+v];
  }
}

// ============ 5. attention (tiled NN GEMM, rowsum fused) ============
__global__ __launch_bounds__(256) void k_att(
    const float* __restrict__ alpha, const float* __restrict__ hs,
    float* __restrict__ att)
{
  const int z = blockIdx.z;
  const float* A = alpha + (size_t)z*LQ*LQ;
  const float* B = hs + (size_t)(z?3:2)*LQ*HH;
  float* outp = att + (size_t)z*LQ*HH;
  __shared__ float As[16][68], Bs[16][68];
  const int tid = threadIdx.x;
  const int tx = tid & 15, ty = tid >> 4;
  const int i0 = blockIdx.y*64, h0 = blockIdx.x*64;
  float acc[4][4] = {};
  float rsum[4] = {};
  for (int j0=0;j0<LQ;j0+=16){
    for (int idx=tid; idx<1024; idx+=256){
      int r = idx>>4, kk = idx&15;
      As[kk][r] = A[(size_t)(i0+r)*LQ + j0+kk];
    }
    for (int idx=tid; idx<1024; idx+=256){
      int jjr = idx>>6, hh = idx&63;
      Bs[jjr][hh] = B[(size_t)(j0+jjr)*HH + h0+hh];
    }
    __syncthreads();
    #pragma unroll
    for (int kk=0;kk<16;kk++){
      float a[4], b[4];
      #pragma unroll
      for (int u=0;u<4;u++){ a[u]=As[kk][ty*4+u]; rsum[u] += a[u]; }
      #pragma unroll
      for (int v=0;v<4;v++) b[v]=Bs[kk][tx*4+v];
      #pragma unroll
      for (int u=0;u<4;u++)
        #pragma unroll
        for (int v=0;v<4;v++) acc[u][v] = fmaf(a[u], b[v], acc[u][v]);
    }
    __syncthreads();
  }
  #pragma unroll
  for (int u=0;u<4;u++){
    float inv = 1.f/rsum[u];
    #pragma unroll
    for (int v=0;v<4;v++)
      outp[(size_t)(i0+ty*4+u)*HH + h0+tx*4+v] = acc[u][v]*inv;
  }
}

// ============ 6. fused wcos_rows: outputs m = 0,1,4,5 ============
__global__ __launch_bounds__(256) void k_wcos(
    const float* __restrict__ hs, const float* __restrict__ att,
    const float* __restrict__ W1, const float* __restrict__ W2, const float* __restrict__ W5,
    float* __restrict__ outp)
{
  const int l = blockIdx.x;
  const int which = blockIdx.y;
  const int tid = threadIdx.x;
  const float* a; const float* c; const float* Wt; int m;
  switch (which) {
    case 0:  a = hs + (size_t)0*LQ*HH + (size_t)l*HH; c = hs + (size_t)2*LQ*HH + (size_t)(LQ-1)*HH; Wt = W1; m = 0; break;
    case 1:  a = hs + (size_t)1*LQ*HH + (size_t)l*HH; c = hs + (size_t)3*LQ*HH;                     Wt = W2; m = 1; break;
    case 2:  a = hs + (size_t)0*LQ*HH + (size_t)l*HH; c = att + (size_t)0*LQ*HH + (size_t)l*HH;     Wt = W5; m = 4; break;
    default: a = hs + (size_t)1*LQ*HH + (size_t)l*HH; c = att + (size_t)1*LQ*HH + (size_t)l*HH;     Wt = W5; m = 5; break;
  }
  __shared__ float av[HH], cv[HH];
  __shared__ float scr[4];
  av[tid]=a[tid]; av[tid+256]=a[tid+256];
  cv[tid]=c[tid]; cv[tid+256]=c[tid+256];
  __syncthreads();
  for (int k=0;k<WW;k++){
    float w1 = Wt[(size_t)k*HH+tid];
    float w2 = Wt[(size_t)k*HH+tid+256];
    float aw1=av[tid]*w1, aw2=av[tid+256]*w2;
    float cw1=cv[tid]*w1, cw2=cv[tid+256]*w2;
    float num = blk_sum(aw1*cw1 + aw2*cw2, scr, tid);
    float na  = blk_sum(aw1*aw1 + aw2*aw2, scr, tid);
    float nc  = blk_sum(cw1*cw1 + cw2*cw2, scr, tid);
    if (tid==0){
      float d = fmaxf(sqrtf(na),EPSF)*fmaxf(sqrtf(nc),EPSF);
      outp[((size_t)m*LQ + l)*WW + k] = num/d;
    }
  }
}

// ============ 7. pair_max (tiled GEMM w/ fused max over j): outputs m = 2,3 ============
__global__ __launch_bounds__(256) void k_pairmax(
    const float* __restrict__ hs, const float* __restrict__ W3, const float* __restrict__ W4,
    const float* __restrict__ nrm, float* __restrict__ outp)
{
  const int k  = blockIdx.x;   // 0..19
  const int it = blockIdx.y;   // 0..7
  const int mm = blockIdx.z;   // 0:pos 1:neg
  const float* A = hs + (size_t)(mm?1:0)*LQ*HH;
  const float* B = hs + (size_t)(mm?3:2)*LQ*HH;
  const float* Wt = mm ? W4 : W3;
  const float* na = nrm + (size_t)(mm?2:0)*LQ*WW;
  const float* nb = nrm + (size_t)(mm?3:1)*LQ*WW;
  const int tid = threadIdx.x;
  const int tx = tid & 15, ty = tid >> 4;
  __shared__ float w2[HH];
  __shared__ float nbinv[LQ];
  __shared__ float As[16][68], Bs[16][68];
  for (int h=tid; h<HH; h+=256){ float wv = Wt[(size_t)k*HH + h]; w2[h]=wv*wv; }
  for (int j=tid; j<LQ; j+=256){ nbinv[j] = 1.f/nb[(size_t)j*WW + k]; }
  __syncthreads();
  const int i0 = it*64;
  float vmax[4] = {-3.4e38f,-3.4e38f,-3.4e38f,-3.4e38f};
  for (int j0=0;j0<LQ;j0+=64){
    float acc[4][4] = {};
    for (int k0=0;k0<HH;k0+=16){
      for (int idx=tid; idx<1024; idx+=256){
        int r=idx>>4, kk=idx&15;
        As[kk][r] = A[(size_t)(i0+r)*HH + k0+kk] * w2[k0+kk];
      }
      for (int idx=tid; idx<1024; idx+=256){
        int r=idx>>4, kk=idx&15;
        Bs[kk][r] = B[(size_t)(j0+r)*HH + k0+kk];
      }
      __syncthreads();
      #pragma unroll
      for (int kk=0;kk<16;kk++){
        float a[4], b[4];
        #pragma unroll
        for (int u=0;u<4;u++) a[u]=As[kk][ty*4+u];
        #pragma unroll
        for (int v=0;v<4;v++) b[v]=Bs[kk][tx*4+v];
        #pragma unroll
        for (int u=0;u<4;u++)
          #pragma unroll
          for (int v=0;v<4;v++) acc[u][v] = fmaf(a[u], b[v], acc[u][v]);
      }
      __syncthreads();
    }
    #pragma unroll
    for (int v=0;v<4;v++){
      float nv = nbinv[j0+tx*4+v];
      #pragma unroll
      for (int u=0;u<4;u++)
        vmax[u] = fmaxf(vmax[u], acc[u][v]*nv);
    }
  }
  #pragma unroll
  for (int o=1;o<16;o<<=1){
    #pragma unroll
    for (int u=0;u<4;u++)
      vmax[u] = fmaxf(vmax[u], __shfl_xor(vmax[u], o, 16));
  }
  if (tx==0){
    #pragma unroll
    for (int u=0;u<4;u++){
      int i = i0 + ty*4 + u;
      outp[((size_t)(mm+2)*LQ + i)*WW + k] = vmax[u] / na[(size_t)i*WW + k];
    }
  }
}

extern "C" void kernel_launch(void* const* d_in, const int* in_sizes, int n_in,
                              void* d_out, int out_size, void* d_ws, size_t ws_size,
                              hipStream_t stream)
{
  float* outp = (float*)d_out;

  float code = 0.f;
  if (n_in != 19)                    code = 101.f;
  else if (in_sizes[0]  != 512)      code = 102.f;
  else if (in_sizes[4]  != 9000000)  code = 104.f;
  else if (in_sizes[6]  != 1048576)  code = 106.f;
  else if (out_size     != 61440)    code = 108.f;
  else if (ws_size      < WS_NEEDED) code = 109.f;
  if (code != 0.f) {
    k_sentinel<<<12, 256, 0, stream>>>(outp, code);
    return;
  }

  const int* q1_ids = (const int*)d_in[0];
  const int* q2_ids = (const int*)d_in[1];
  const float* emb      = (const float*)d_in[4];
  const float* q1_wih_f = (const float*)d_in[5];
  const float* q1_whh_f = (const float*)d_in[6];
  const float* q1_wih_b = (const float*)d_in[7];
  const float* q1_whh_b = (const float*)d_in[8];
  const float* q2_wih_f = (const float*)d_in[9];
  const float* q2_whh_f = (const float*)d_in[10];
  const float* q2_wih_b = (const float*)d_in[11];
  const float* q2_whh_b = (const float*)d_in[12];
  const float* W1 = (const float*)d_in[13];
  const float* W2 = (const float*)d_in[14];
  const float* W3 = (const float*)d_in[15];
  const float* W4 = (const float*)d_in[16];
  const float* W5 = (const float*)d_in[17];
  float* ws = (float*)d_ws;

  float* gin   = ws + OFF_GIN;
  float* hsv   = ws + OFF_HS;
  u64*   hpub  = (u64*)(ws + OFF_HPUB);
  float* alpha = ws + OFF_ALPHA;
  float* att   = ws + OFF_ATT;
  float* nrm   = ws + OFF_NRM;
  float* np_   = ws + OFF_NP;

  k_gather_gemm<<<dim3(32,8,4), 256, 0, stream>>>(emb, q1_ids, q2_ids,
      q1_wih_f, q1_wih_b, q2_wih_f, q2_wih_b, gin);
  k_lstm<<<dim3(4*RB), 512, 0, stream>>>(q1_whh_f, q1_whh_b, q2_whh_f, q2_whh_b,
      gin, hsv, hpub);
  k_norms<<<dim3(LQ,4), 256, 0, stream>>>(hsv, W3, W4, nrm, np_);
  k_alpha<<<dim3(8,8,2), 256, 0, stream>>>(hsv, np_, alpha);
  k_att<<<dim3(8,8,2), 256, 0, stream>>>(alpha, hsv, att);
  k_wcos<<<dim3(LQ,4), 256, 0, stream>>>(hsv, att, W1, W2, W5, outp);
  k_pairmax<<<dim3(WW,8,2), 256, 0, stream>>>(hsv, W3, W4, nrm, outp);
}